// Round 1
// baseline (1009.570 us; speedup 1.0000x reference)
//
#include <hip/hip_runtime.h>

// MultiHeadattention: B=2, S=2048, D=1024, H=16, Dk=64.
// QUIRK: softmax over the HEAD axis (dim=1), i.e. attn[b,h,q,k] = exp(s)/sum_h' exp(s).
// Pipeline: 3x proj GEMM (bf16 MFMA, V written transposed) -> fused attention
// (head-softmax local per (q,k)) with K-split=2 partials -> out-proj GEMM (sums partials).

#define D_MODEL 1024
#define NH 16
#define DKH 64
#define SEQ 2048
#define NB 2
#define NTOK (NB * SEQ)
#define SCALE 0.125f

typedef float f32x4 __attribute__((ext_vector_type(4)));
typedef short bf16x8 __attribute__((ext_vector_type(8)));

static __device__ __forceinline__ float bf2f(unsigned short h) {
    union { unsigned int u; float f; } c; c.u = ((unsigned int)h) << 16; return c.f;
}
static __device__ __forceinline__ unsigned short f2bf(float x) {
    union { float f; unsigned int u; } c; c.f = x;
    unsigned int r = (c.u + 0x7FFFu + ((c.u >> 16) & 1u)) >> 16;
    return (unsigned short)r;
}
static __device__ __forceinline__ unsigned int pack2(float a, float b) {
    return (unsigned int)f2bf(a) | ((unsigned int)f2bf(b) << 16);
}
static __device__ __forceinline__ float bflo(unsigned int u) {
    union { unsigned int x; float f; } c; c.x = u << 16; return c.f;
}
static __device__ __forceinline__ float bfhi(unsigned int u) {
    union { unsigned int x; float f; } c; c.x = u & 0xFFFF0000u; return c.f;
}
static __device__ __forceinline__ f32x4 mfma16(uint4 a, uint4 b, f32x4 c) {
    return __builtin_amdgcn_mfma_f32_16x16x32_bf16(
        __builtin_bit_cast(bf16x8, a), __builtin_bit_cast(bf16x8, b), c, 0, 0, 0);
}

// ---------------- Projection GEMM: out[m,n] = sum_k X[m,k]*W[n,k] + bias[n] ----------------
// MODE 0: bf16 out [token][n].  MODE 1: bf16 out transposed Vt[(b*1024+n)*2048 + s].
template <int MODE>
__global__ __launch_bounds__(256) void proj_kernel(
    const float* __restrict__ X, const float* __restrict__ W,
    const float* __restrict__ bias, unsigned short* __restrict__ out)
{
    __shared__ unsigned short lA[64 * 64];
    __shared__ unsigned short lB[64 * 64];
    const int tid = threadIdx.x;
    const int wv = tid >> 6, lane = tid & 63, quad = lane >> 4, lm = lane & 15;
    const int m0 = blockIdx.y * 64, n0 = blockIdx.x * 64;

    f32x4 acc[4] = {};

    for (int k0 = 0; k0 < D_MODEL; k0 += 64) {
        __syncthreads();
#pragma unroll
        for (int r = 0; r < 2; ++r) {
            int idx = r * 256 + tid;
            int row = idx >> 3, ch = idx & 7, phys = ch ^ (row & 7);
            const float* ga = X + (size_t)(m0 + row) * D_MODEL + k0 + ch * 8;
            float4 a0 = *(const float4*)ga;
            float4 a1 = *(const float4*)(ga + 4);
            uint4 pa = { pack2(a0.x, a0.y), pack2(a0.z, a0.w),
                         pack2(a1.x, a1.y), pack2(a1.z, a1.w) };
            *(uint4*)&lA[row * 64 + phys * 8] = pa;
            const float* gb = W + (size_t)(n0 + row) * D_MODEL + k0 + ch * 8;
            float4 b0 = *(const float4*)gb;
            float4 b1 = *(const float4*)(gb + 4);
            uint4 pb = { pack2(b0.x, b0.y), pack2(b0.z, b0.w),
                         pack2(b1.x, b1.y), pack2(b1.z, b1.w) };
            *(uint4*)&lB[row * 64 + phys * 8] = pb;
        }
        __syncthreads();
#pragma unroll
        for (int ks = 0; ks < 2; ++ks) {
            int arow = wv * 16 + lm;
            int ach = ks * 4 + quad;
            uint4 af = *(const uint4*)&lA[arow * 64 + (ach ^ (lm & 7)) * 8];
#pragma unroll
            for (int nt = 0; nt < 4; ++nt) {
                int brow = nt * 16 + lm;
                uint4 bf = *(const uint4*)&lB[brow * 64 + (ach ^ (lm & 7)) * 8];
                acc[nt] = mfma16(af, bf, acc[nt]);
            }
        }
    }
#pragma unroll
    for (int nt = 0; nt < 4; ++nt) {
        int n = n0 + nt * 16 + lm;
        float bv = bias[n];
#pragma unroll
        for (int r = 0; r < 4; ++r) {
            int m = m0 + wv * 16 + quad * 4 + r;
            float v = acc[nt][r] + bv;
            if (MODE == 0) {
                out[(size_t)m * D_MODEL + n] = f2bf(v);
            } else {
                int bi = m >> 11, s = m & 2047;
                out[((size_t)(bi * D_MODEL + n)) * SEQ + s] = f2bf(v);
            }
        }
    }
}

// ---------------- Out-projection: context = P0+P1 (bf16 partials), fp32 output ----------------
__global__ __launch_bounds__(256) void oproj_kernel(
    const unsigned short* __restrict__ P0, const unsigned short* __restrict__ P1,
    const float* __restrict__ W, const float* __restrict__ bias, float* __restrict__ out)
{
    __shared__ unsigned short lA[64 * 64];
    __shared__ unsigned short lB[64 * 64];
    const int tid = threadIdx.x;
    const int wv = tid >> 6, lane = tid & 63, quad = lane >> 4, lm = lane & 15;
    const int m0 = blockIdx.y * 64, n0 = blockIdx.x * 64;

    f32x4 acc[4] = {};

    for (int k0 = 0; k0 < D_MODEL; k0 += 64) {
        __syncthreads();
#pragma unroll
        for (int r = 0; r < 2; ++r) {
            int idx = r * 256 + tid;
            int row = idx >> 3, ch = idx & 7, phys = ch ^ (row & 7);
            size_t aoff = (size_t)(m0 + row) * D_MODEL + k0 + ch * 8;
            uint4 u0 = *(const uint4*)(P0 + aoff);
            uint4 u1 = *(const uint4*)(P1 + aoff);
            uint4 pa;
            pa.x = pack2(bflo(u0.x) + bflo(u1.x), bfhi(u0.x) + bfhi(u1.x));
            pa.y = pack2(bflo(u0.y) + bflo(u1.y), bfhi(u0.y) + bfhi(u1.y));
            pa.z = pack2(bflo(u0.z) + bflo(u1.z), bfhi(u0.z) + bfhi(u1.z));
            pa.w = pack2(bflo(u0.w) + bflo(u1.w), bfhi(u0.w) + bfhi(u1.w));
            *(uint4*)&lA[row * 64 + phys * 8] = pa;
            const float* gb = W + (size_t)(n0 + row) * D_MODEL + k0 + ch * 8;
            float4 b0 = *(const float4*)gb;
            float4 b1 = *(const float4*)(gb + 4);
            uint4 pb = { pack2(b0.x, b0.y), pack2(b0.z, b0.w),
                         pack2(b1.x, b1.y), pack2(b1.z, b1.w) };
            *(uint4*)&lB[row * 64 + phys * 8] = pb;
        }
        __syncthreads();
#pragma unroll
        for (int ks = 0; ks < 2; ++ks) {
            int arow = wv * 16 + lm;
            int ach = ks * 4 + quad;
            uint4 af = *(const uint4*)&lA[arow * 64 + (ach ^ (lm & 7)) * 8];
#pragma unroll
            for (int nt = 0; nt < 4; ++nt) {
                int brow = nt * 16 + lm;
                uint4 bf = *(const uint4*)&lB[brow * 64 + (ach ^ (lm & 7)) * 8];
                acc[nt] = mfma16(af, bf, acc[nt]);
            }
        }
    }
#pragma unroll
    for (int nt = 0; nt < 4; ++nt) {
        int n = n0 + nt * 16 + lm;
        float bv = bias[n];
#pragma unroll
        for (int r = 0; r < 4; ++r) {
            int m = m0 + wv * 16 + quad * 4 + r;
            out[(size_t)m * D_MODEL + n] = acc[nt][r] + bv;
        }
    }
}

// ---------------- Fused attention with head-axis softmax ----------------
// Block: (q-tile of 32, batch b, K-half). 4 waves x 4 heads. Tk=16 keys/iter.
__global__ __launch_bounds__(256, 2) void attn_kernel(
    const unsigned short* __restrict__ Qb, const unsigned short* __restrict__ Kb,
    const unsigned short* __restrict__ Vt, unsigned short* __restrict__ OP)
{
    __shared__ unsigned short kv[20480];  // K tile: [16 key][128 ch16 swizzled] (32KB) / Vt tile: [1024 c][20 u16] (40KB)
    __shared__ unsigned short ep[10240];  // E/P: [16 h][32 q][20 u16] bf16 (20KB)
    __shared__ float zbuf[512];           // Z then 1/Z: [32 q][16 k]

    const int tid = threadIdx.x;
    const int wv = tid >> 6, lane = tid & 63, quad = lane >> 4, lm = lane & 15;
    const int q0 = blockIdx.x * 32;
    const int b = blockIdx.y;
    const int kh = blockIdx.z;
    const int kbase = kh * 1024;

    // Q fragments (A-operand): lane holds Q[q = lane&15][dk = quad*8 + j]
    uint4 qf[4][2][2];
#pragma unroll
    for (int hh = 0; hh < 4; ++hh) {
        int h = wv * 4 + hh;
#pragma unroll
        for (int mt = 0; mt < 2; ++mt)
#pragma unroll
            for (int ks = 0; ks < 2; ++ks) {
                size_t off = (size_t)(b * SEQ + q0 + mt * 16 + lm) * D_MODEL
                           + h * DKH + ks * 32 + quad * 8;
                qf[hh][mt][ks] = *(const uint4*)(Qb + off);
            }
    }
    f32x4 oa[4][2][4] = {};

    for (int kt = 0; kt < 64; ++kt) {
        const int k0 = kbase + kt * 16;
        __syncthreads();                       // prev iter's PV done: safe to overwrite kv/zbuf
        zbuf[tid] = 0.f;
        zbuf[tid + 256] = 0.f;
#pragma unroll
        for (int i = 0; i < 8; ++i) {          // stage K tile (swizzled 16B chunks)
            int g = i * 256 + tid;
            int key = g >> 7, ch = g & 127, phys = ch ^ (key & 7);
            size_t off = (size_t)(b * SEQ + k0 + key) * D_MODEL + ch * 8;
            *(uint4*)&kv[key * 1024 + phys * 8] = *(const uint4*)(Kb + off);
        }
        __syncthreads();                       // K staged, Z zeroed

        float zacc[2][4] = {};
#pragma unroll
        for (int hh = 0; hh < 4; ++hh) {
            int h = wv * 4 + hh;
            f32x4 sf0 = {0.f, 0.f, 0.f, 0.f};
            f32x4 sf1 = {0.f, 0.f, 0.f, 0.f};
#pragma unroll
            for (int ks = 0; ks < 2; ++ks) {
                int chunk = h * 8 + ks * 4 + quad;
                uint4 kf = *(const uint4*)&kv[lm * 1024 + (chunk ^ (lm & 7)) * 8];
                sf0 = mfma16(qf[hh][0][ks], kf, sf0);
                sf1 = mfma16(qf[hh][1][ks], kf, sf1);
            }
#pragma unroll
            for (int r = 0; r < 4; ++r) {
                float e0 = __expf(sf0[r] * SCALE);
                float e1 = __expf(sf1[r] * SCALE);
                zacc[0][r] += e0;
                zacc[1][r] += e1;
                ep[h * 640 + (quad * 4 + r) * 20 + lm] = f2bf(e0);
                ep[h * 640 + (16 + quad * 4 + r) * 20 + lm] = f2bf(e1);
            }
        }
#pragma unroll
        for (int mt = 0; mt < 2; ++mt)
#pragma unroll
            for (int r = 0; r < 4; ++r)
                atomicAdd(&zbuf[(mt * 16 + quad * 4 + r) * 16 + lm], zacc[mt][r]);
        __syncthreads();                       // E + Z complete; K reads done

        zbuf[tid] = 1.0f / zbuf[tid];
        zbuf[tid + 256] = 1.0f / zbuf[tid + 256];
#pragma unroll
        for (int i = 0; i < 16; ++i) {         // stage V^T tile over K's region
            int g = i * 256 + tid;
            int c = g >> 2, part = g & 3;
            size_t off = (size_t)(b * D_MODEL + c) * SEQ + k0 + part * 4;
            *(uint2*)&kv[c * 20 + part * 4] = *(const uint2*)(Vt + off);
        }
        __syncthreads();                       // V^T + 1/Z ready

#pragma unroll
        for (int hh = 0; hh < 4; ++hh) {
            int h = wv * 4 + hh;
            uint4 af[2];
#pragma unroll
            for (int mt = 0; mt < 2; ++mt) {
                uint4 pk = {0u, 0u, 0u, 0u};
                if (quad < 2) {                // k = quad*8 + j in [0,16); quads 2,3 supply zeros
                    int base = h * 640 + (mt * 16 + lm) * 20 + quad * 8;
                    ushort4 e0 = *(const ushort4*)&ep[base];
                    ushort4 e1 = *(const ushort4*)&ep[base + 4];
                    int zb = (mt * 16 + lm) * 16 + quad * 8;
                    float4 z0 = *(const float4*)&zbuf[zb];
                    float4 z1 = *(const float4*)&zbuf[zb + 4];
                    pk.x = pack2(bf2f(e0.x) * z0.x, bf2f(e0.y) * z0.y);
                    pk.y = pack2(bf2f(e0.z) * z0.z, bf2f(e0.w) * z0.w);
                    pk.z = pack2(bf2f(e1.x) * z1.x, bf2f(e1.y) * z1.y);
                    pk.w = pack2(bf2f(e1.z) * z1.z, bf2f(e1.w) * z1.w);
                }
                af[mt] = pk;
            }
#pragma unroll
            for (int nt = 0; nt < 4; ++nt) {
                int c = h * DKH + nt * 16 + lm;
                uint4 pv = {0u, 0u, 0u, 0u};
                if (quad < 2) {
                    int base = c * 20 + quad * 8;
                    uint2 v0 = *(const uint2*)&kv[base];
                    uint2 v1 = *(const uint2*)&kv[base + 4];
                    pv.x = v0.x; pv.y = v0.y; pv.z = v1.x; pv.w = v1.y;
                }
                oa[hh][0][nt] = mfma16(af[0], pv, oa[hh][0][nt]);
                oa[hh][1][nt] = mfma16(af[1], pv, oa[hh][1][nt]);
            }
        }
    }

    unsigned short* outp = OP + (size_t)kh * NTOK * D_MODEL;
#pragma unroll
    for (int hh = 0; hh < 4; ++hh)
#pragma unroll
        for (int mt = 0; mt < 2; ++mt)
#pragma unroll
            for (int nt = 0; nt < 4; ++nt)
#pragma unroll
                for (int r = 0; r < 4; ++r) {
                    int m = b * SEQ + q0 + mt * 16 + quad * 4 + r;
                    int cc = (wv * 4 + hh) * DKH + nt * 16 + lm;
                    outp[(size_t)m * D_MODEL + cc] = f2bf(oa[hh][mt][nt][r]);
                }
}

extern "C" void kernel_launch(void* const* d_in, const int* in_sizes, int n_in,
                              void* d_out, int out_size, void* d_ws, size_t ws_size,
                              hipStream_t stream)
{
    const float* x  = (const float*)d_in[0];
    const float* Wq = (const float*)d_in[1];
    const float* bq = (const float*)d_in[2];
    const float* Wk = (const float*)d_in[3];
    const float* bk = (const float*)d_in[4];
    const float* Wv = (const float*)d_in[5];
    const float* bv = (const float*)d_in[6];
    const float* Wo = (const float*)d_in[7];
    const float* bo = (const float*)d_in[8];
    float* out = (float*)d_out;

    unsigned short* ws = (unsigned short*)d_ws;
    unsigned short* Qb = ws;                                   // [4096][1024] bf16
    unsigned short* Kb = Qb + (size_t)NTOK * D_MODEL;          // [4096][1024] bf16
    unsigned short* Vt = Kb + (size_t)NTOK * D_MODEL;          // [2][1024][2048] bf16 (transposed)
    unsigned short* OP = Vt + (size_t)NTOK * D_MODEL;          // 2 partials [4096][1024] bf16
    // total ws use: 5 * 8 MB = 40 MB

    dim3 pg(16, 64);
    proj_kernel<0><<<pg, 256, 0, stream>>>(x, Wq, bq, Qb);
    proj_kernel<0><<<pg, 256, 0, stream>>>(x, Wk, bk, Kb);
    proj_kernel<1><<<pg, 256, 0, stream>>>(x, Wv, bv, Vt);
    attn_kernel<<<dim3(64, NB, 2), 256, 0, stream>>>(Qb, Kb, Vt, OP);
    oproj_kernel<<<pg, 256, 0, stream>>>(OP, OP + (size_t)NTOK * D_MODEL, Wo, bo, out);
}

// Round 3
// 530.671 us; speedup vs baseline: 1.9024x; 1.9024x over previous
//
#include <hip/hip_runtime.h>

// MultiHeadattention: B=2, S=2048, D=1024, H=16, Dk=64.
// QUIRK: softmax over the HEAD axis (dim=1): attn[b,h,q,k] = exp(s)/sum_h' exp(s').
// Pipeline:
//   3x proj GEMM (bf16 MFMA; V written transposed Vt[b][c][s])
//   zker:  rz[b][q][k] = 1/sum_h exp(S_h[q,k]*scale)   (register-only head reduction)
//   attn2: per (b,h,q-tile,ksplit): recompute S^T, p = exp(s)*rz, PV at full K=32
//          via permuted key rows; writes bf16 context partials
//   oproj: sums partials, GEMM with Wo, fp32 out.
// R2->R3 fix: attn2 k-loop advance for kp is key-row stride (32*D_MODEL), not 32.

#define D_MODEL 1024
#define NH 16
#define DKH 64
#define SEQ 2048
#define NB 2
#define NTOK (NB * SEQ)
#define SCALE 0.125f

typedef float f32x4 __attribute__((ext_vector_type(4)));
typedef short bf16x8 __attribute__((ext_vector_type(8)));

static __device__ __forceinline__ float bf2f(unsigned short h) {
    union { unsigned int u; float f; } c; c.u = ((unsigned int)h) << 16; return c.f;
}
static __device__ __forceinline__ unsigned short f2bf(float x) {
    union { float f; unsigned int u; } c; c.f = x;
    unsigned int r = (c.u + 0x7FFFu + ((c.u >> 16) & 1u)) >> 16;
    return (unsigned short)r;
}
static __device__ __forceinline__ unsigned int pack2(float a, float b) {
    return (unsigned int)f2bf(a) | ((unsigned int)f2bf(b) << 16);
}
// one v_perm_b32: result = [hi16(b+rnd) : hi16(a+rnd)] (low half = a)
static __device__ __forceinline__ unsigned int pack2rn(float a, float b) {
    union { float f; unsigned int u; } ca, cb; ca.f = a; cb.f = b;
    return __builtin_amdgcn_perm(cb.u + 0x8000u, ca.u + 0x8000u, 0x07060302u);
}
static __device__ __forceinline__ float bflo(unsigned int u) {
    union { unsigned int x; float f; } c; c.x = u << 16; return c.f;
}
static __device__ __forceinline__ float bfhi(unsigned int u) {
    union { unsigned int x; float f; } c; c.x = u & 0xFFFF0000u; return c.f;
}
static __device__ __forceinline__ f32x4 mfma16(uint4 a, uint4 b, f32x4 c) {
    return __builtin_amdgcn_mfma_f32_16x16x32_bf16(
        __builtin_bit_cast(bf16x8, a), __builtin_bit_cast(bf16x8, b), c, 0, 0, 0);
}

// ---------------- Projection GEMM: out[m,n] = sum_k X[m,k]*W[n,k] + bias[n] ----------------
// MODE 0: bf16 out [token][n].  MODE 1: bf16 out transposed Vt[(b*1024+n)*2048 + s].
template <int MODE>
__global__ __launch_bounds__(256) void proj_kernel(
    const float* __restrict__ X, const float* __restrict__ W,
    const float* __restrict__ bias, unsigned short* __restrict__ out)
{
    __shared__ unsigned short lA[64 * 64];
    __shared__ unsigned short lB[64 * 64];
    const int tid = threadIdx.x;
    const int wv = tid >> 6, lane = tid & 63, quad = lane >> 4, lm = lane & 15;
    const int m0 = blockIdx.y * 64, n0 = blockIdx.x * 64;

    f32x4 acc[4] = {};

    for (int k0 = 0; k0 < D_MODEL; k0 += 64) {
        __syncthreads();
#pragma unroll
        for (int r = 0; r < 2; ++r) {
            int idx = r * 256 + tid;
            int row = idx >> 3, ch = idx & 7, phys = ch ^ (row & 7);
            const float* ga = X + (size_t)(m0 + row) * D_MODEL + k0 + ch * 8;
            float4 a0 = *(const float4*)ga;
            float4 a1 = *(const float4*)(ga + 4);
            uint4 pa = { pack2(a0.x, a0.y), pack2(a0.z, a0.w),
                         pack2(a1.x, a1.y), pack2(a1.z, a1.w) };
            *(uint4*)&lA[row * 64 + phys * 8] = pa;
            const float* gb = W + (size_t)(n0 + row) * D_MODEL + k0 + ch * 8;
            float4 b0 = *(const float4*)gb;
            float4 b1 = *(const float4*)(gb + 4);
            uint4 pb = { pack2(b0.x, b0.y), pack2(b0.z, b0.w),
                         pack2(b1.x, b1.y), pack2(b1.z, b1.w) };
            *(uint4*)&lB[row * 64 + phys * 8] = pb;
        }
        __syncthreads();
#pragma unroll
        for (int ks = 0; ks < 2; ++ks) {
            int arow = wv * 16 + lm;
            int ach = ks * 4 + quad;
            uint4 af = *(const uint4*)&lA[arow * 64 + (ach ^ (lm & 7)) * 8];
#pragma unroll
            for (int nt = 0; nt < 4; ++nt) {
                int brow = nt * 16 + lm;
                uint4 bf = *(const uint4*)&lB[brow * 64 + (ach ^ (lm & 7)) * 8];
                acc[nt] = mfma16(af, bf, acc[nt]);
            }
        }
    }
#pragma unroll
    for (int nt = 0; nt < 4; ++nt) {
        int n = n0 + nt * 16 + lm;
        float bv = bias[n];
#pragma unroll
        for (int r = 0; r < 4; ++r) {
            int m = m0 + wv * 16 + quad * 4 + r;
            float v = acc[nt][r] + bv;
            if (MODE == 0) {
                out[(size_t)m * D_MODEL + n] = f2bf(v);
            } else {
                int bi = m >> 11, s = m & 2047;
                out[((size_t)(bi * D_MODEL + n)) * SEQ + s] = f2bf(v);
            }
        }
    }
}

// ---------------- Out-projection: context = P0 (+P1), fp32 output ----------------
template <int TWO>
__global__ __launch_bounds__(256) void oproj_kernel(
    const unsigned short* __restrict__ P0, const unsigned short* __restrict__ P1,
    const float* __restrict__ W, const float* __restrict__ bias, float* __restrict__ out)
{
    __shared__ unsigned short lA[64 * 64];
    __shared__ unsigned short lB[64 * 64];
    const int tid = threadIdx.x;
    const int wv = tid >> 6, lane = tid & 63, quad = lane >> 4, lm = lane & 15;
    const int m0 = blockIdx.y * 64, n0 = blockIdx.x * 64;

    f32x4 acc[4] = {};

    for (int k0 = 0; k0 < D_MODEL; k0 += 64) {
        __syncthreads();
#pragma unroll
        for (int r = 0; r < 2; ++r) {
            int idx = r * 256 + tid;
            int row = idx >> 3, ch = idx & 7, phys = ch ^ (row & 7);
            size_t aoff = (size_t)(m0 + row) * D_MODEL + k0 + ch * 8;
            uint4 pa;
            if (TWO) {
                uint4 u0 = *(const uint4*)(P0 + aoff);
                uint4 u1 = *(const uint4*)(P1 + aoff);
                pa.x = pack2(bflo(u0.x) + bflo(u1.x), bfhi(u0.x) + bfhi(u1.x));
                pa.y = pack2(bflo(u0.y) + bflo(u1.y), bfhi(u0.y) + bfhi(u1.y));
                pa.z = pack2(bflo(u0.z) + bflo(u1.z), bfhi(u0.z) + bfhi(u1.z));
                pa.w = pack2(bflo(u0.w) + bflo(u1.w), bfhi(u0.w) + bfhi(u1.w));
            } else {
                pa = *(const uint4*)(P0 + aoff);
            }
            *(uint4*)&lA[row * 64 + phys * 8] = pa;
            const float* gb = W + (size_t)(n0 + row) * D_MODEL + k0 + ch * 8;
            float4 b0 = *(const float4*)gb;
            float4 b1 = *(const float4*)(gb + 4);
            uint4 pb = { pack2(b0.x, b0.y), pack2(b0.z, b0.w),
                         pack2(b1.x, b1.y), pack2(b1.z, b1.w) };
            *(uint4*)&lB[row * 64 + phys * 8] = pb;
        }
        __syncthreads();
#pragma unroll
        for (int ks = 0; ks < 2; ++ks) {
            int arow = wv * 16 + lm;
            int ach = ks * 4 + quad;
            uint4 af = *(const uint4*)&lA[arow * 64 + (ach ^ (lm & 7)) * 8];
#pragma unroll
            for (int nt = 0; nt < 4; ++nt) {
                int brow = nt * 16 + lm;
                uint4 bf = *(const uint4*)&lB[brow * 64 + (ach ^ (lm & 7)) * 8];
                acc[nt] = mfma16(af, bf, acc[nt]);
            }
        }
    }
#pragma unroll
    for (int nt = 0; nt < 4; ++nt) {
        int n = n0 + nt * 16 + lm;
        float bv = bias[n];
#pragma unroll
        for (int r = 0; r < 4; ++r) {
            int m = m0 + wv * 16 + quad * 4 + r;
            out[(size_t)m * D_MODEL + n] = acc[nt][r] + bv;
        }
    }
}

// ---------------- Phase 1: rz[b][q][k] = 1/sum_h exp(S_h[q,k]*scale) ----------------
// Block: 4 waves; wave w owns q-subtile (16 rows), block covers q64 x k64. No LDS.
// A = Q (m=q), B = K (n=k)  ->  C-layout lane holds q=quad*4+r, k=lm: same (q,k)
// across ALL heads -> Z is a per-lane register sum. rz write contiguous in k.
__global__ __launch_bounds__(256, 4) void zker(
    const unsigned short* __restrict__ Qb, const unsigned short* __restrict__ Kb,
    unsigned short* __restrict__ rz)
{
    const int tid = threadIdx.x;
    const int wv = tid >> 6, lane = tid & 63, quad = lane >> 4, lm = lane & 15;
    const int kb = blockIdx.x, qb = blockIdx.y, b = blockIdx.z;
    const int q0w = qb * 64 + wv * 16;
    const int k0 = kb * 64;

    const unsigned short* qrow = Qb + (size_t)(b * SEQ + q0w + lm) * D_MODEL + quad * 8;
    const unsigned short* krow = Kb + (size_t)(b * SEQ + k0 + lm) * D_MODEL + quad * 8;

    f32x4 z[4] = {};

#pragma unroll
    for (int h = 0; h < NH; ++h) {
        uint4 af0 = *(const uint4*)(qrow + h * DKH);
        uint4 af1 = *(const uint4*)(qrow + h * DKH + 32);
#pragma unroll
        for (int ksub = 0; ksub < 4; ++ksub) {
            const unsigned short* kr = krow + (size_t)ksub * 16 * D_MODEL + h * DKH;
            uint4 bf0 = *(const uint4*)kr;
            uint4 bf1 = *(const uint4*)(kr + 32);
            f32x4 sf = {0.f, 0.f, 0.f, 0.f};
            sf = mfma16(af0, bf0, sf);
            sf = mfma16(af1, bf1, sf);
#pragma unroll
            for (int r = 0; r < 4; ++r)
                z[ksub][r] += __expf(sf[r] * SCALE);
        }
    }
#pragma unroll
    for (int ksub = 0; ksub < 4; ++ksub)
#pragma unroll
        for (int r = 0; r < 4; ++r)
            rz[(size_t)(b * SEQ + q0w + quad * 4 + r) * SEQ + k0 + ksub * 16 + lm] =
                f2bf(1.0f / z[ksub][r]);
}

// ---------------- Phase 2: per-head attention with precomputed rz ----------------
// Block: (q-tile 128, b*16+h, ksplit). 4 waves, wave = 32 q (2 subtiles). No LDS.
// S^T via A=K with permuted rows perm(m)=(m>>2)*8+(m&3)(+4sel): C-layout then equals
// the K=32 B-fragment layout (k = quad*8 + j), enabling full-K PV MFMAs.
template <int KS>
__global__ __launch_bounds__(256, 2) void attn2(
    const unsigned short* __restrict__ Qb, const unsigned short* __restrict__ Kb,
    const unsigned short* __restrict__ Vt, const unsigned short* __restrict__ rz,
    unsigned short* __restrict__ OP)
{
    const int tid = threadIdx.x;
    const int wv = tid >> 6, lane = tid & 63, quad = lane >> 4, lm = lane & 15;
    const int qb = blockIdx.x;
    const int bh = blockIdx.y, b = bh >> 4, h = bh & 15;
    const int ksl = blockIdx.z;
    const int nk = SEQ / KS;
    const int kbeg = ksl * nk;
    const int q0w = qb * 128 + wv * 32;

    // Q fragments (B-operand; n=q=lm), held across the k-loop
    uint4 qf[2][2];
#pragma unroll
    for (int qs = 0; qs < 2; ++qs)
#pragma unroll
        for (int ks = 0; ks < 2; ++ks)
            qf[qs][ks] = *(const uint4*)(Qb +
                (size_t)(b * SEQ + q0w + qs * 16 + lm) * D_MODEL +
                h * DKH + ks * 32 + quad * 8);

    const int perm = ((lm >> 2) * 8) + (lm & 3);
    const unsigned short* kp = Kb + (size_t)(b * SEQ + kbeg + perm) * D_MODEL + h * DKH + quad * 8;
    const unsigned short* vp = Vt + (size_t)(b * D_MODEL + h * DKH + lm) * SEQ + kbeg + quad * 8;
    const unsigned short* rp = rz + (size_t)(b * SEQ + q0w + lm) * SEQ + kbeg + quad * 8;

    f32x4 oa[4][2] = {};

    for (int kt = 0; kt < nk / 32; ++kt) {
        // K fragments, permuted rows (sel: +4 rows => +4*D_MODEL)
        uint4 kf[2][2];
#pragma unroll
        for (int sel = 0; sel < 2; ++sel)
#pragma unroll
            for (int ks = 0; ks < 2; ++ks)
                kf[sel][ks] = *(const uint4*)(kp + (size_t)sel * 4 * D_MODEL + ks * 32);

        f32x4 sf[2][2] = {};
#pragma unroll
        for (int sel = 0; sel < 2; ++sel)
#pragma unroll
            for (int qs = 0; qs < 2; ++qs)
#pragma unroll
                for (int ks = 0; ks < 2; ++ks)
                    sf[sel][qs] = mfma16(kf[sel][ks], qf[qs][ks], sf[sel][qs]);

        uint2 rv[2][2];
#pragma unroll
        for (int qs = 0; qs < 2; ++qs)
#pragma unroll
            for (int sel = 0; sel < 2; ++sel)
                rv[qs][sel] = *(const uint2*)(rp + (size_t)qs * 16 * SEQ + sel * 4);

        uint4 pk[2];
#pragma unroll
        for (int qs = 0; qs < 2; ++qs) {
            float p[2][4];
#pragma unroll
            for (int sel = 0; sel < 2; ++sel) {
                unsigned int rx = rv[qs][sel].x, ry = rv[qs][sel].y;
                p[sel][0] = __expf(sf[sel][qs][0] * SCALE) * bflo(rx);
                p[sel][1] = __expf(sf[sel][qs][1] * SCALE) * bfhi(rx);
                p[sel][2] = __expf(sf[sel][qs][2] * SCALE) * bflo(ry);
                p[sel][3] = __expf(sf[sel][qs][3] * SCALE) * bfhi(ry);
            }
            pk[qs].x = pack2rn(p[0][0], p[0][1]);
            pk[qs].y = pack2rn(p[0][2], p[0][3]);
            pk[qs].z = pack2rn(p[1][0], p[1][1]);
            pk[qs].w = pack2rn(p[1][2], p[1][3]);
        }

#pragma unroll
        for (int ct = 0; ct < 4; ++ct) {
            uint4 vf = *(const uint4*)(vp + (size_t)ct * 16 * SEQ);
            oa[ct][0] = mfma16(vf, pk[0], oa[ct][0]);
            oa[ct][1] = mfma16(vf, pk[1], oa[ct][1]);
        }
        kp += 32 * (size_t)D_MODEL;   // key-row stride! (R2 bug: was += 32)
        vp += 32; rp += 32;
    }

    unsigned short* op = OP + (size_t)ksl * NTOK * D_MODEL;
#pragma unroll
    for (int ct = 0; ct < 4; ++ct)
#pragma unroll
        for (int qs = 0; qs < 2; ++qs) {
            uint2 st = { pack2rn(oa[ct][qs][0], oa[ct][qs][1]),
                         pack2rn(oa[ct][qs][2], oa[ct][qs][3]) };
            *(uint2*)(op + (size_t)(b * SEQ + q0w + qs * 16 + lm) * D_MODEL +
                      h * DKH + ct * 16 + quad * 4) = st;
        }
}

extern "C" void kernel_launch(void* const* d_in, const int* in_sizes, int n_in,
                              void* d_out, int out_size, void* d_ws, size_t ws_size,
                              hipStream_t stream)
{
    const float* x  = (const float*)d_in[0];
    const float* Wq = (const float*)d_in[1];
    const float* bq = (const float*)d_in[2];
    const float* Wk = (const float*)d_in[3];
    const float* bk = (const float*)d_in[4];
    const float* Wv = (const float*)d_in[5];
    const float* bv = (const float*)d_in[6];
    const float* Wo = (const float*)d_in[7];
    const float* bo = (const float*)d_in[8];
    float* out = (float*)d_out;

    const size_t M = (size_t)NTOK * D_MODEL;       // 4,194,304 elems
    const size_t RZ = (size_t)NB * SEQ * SEQ;      // 8,388,608 elems
    unsigned short* ws = (unsigned short*)d_ws;
    unsigned short* Qb  = ws;            // bf16 [4096][1024]
    unsigned short* Kb  = Qb + M;        // bf16 [4096][1024]
    unsigned short* Vt  = Kb + M;        // bf16 [2][1024][2048]
    unsigned short* rzb = Vt + M;        // bf16 [2][2048][2048]
    unsigned short* OP  = rzb + RZ;      // bf16 partial(s) [4096][1024]

    const size_t need2 = (3 * M + RZ + 2 * M) * sizeof(unsigned short);
    const int KS = (ws_size >= need2) ? 2 : 1;

    dim3 pg(16, 64);
    proj_kernel<0><<<pg, 256, 0, stream>>>(x, Wq, bq, Qb);
    proj_kernel<0><<<pg, 256, 0, stream>>>(x, Wk, bk, Kb);
    proj_kernel<1><<<pg, 256, 0, stream>>>(x, Wv, bv, Vt);
    zker<<<dim3(32, 32, NB), 256, 0, stream>>>(Qb, Kb, rzb);
    if (KS == 2) {
        attn2<2><<<dim3(16, NB * NH, 2), 256, 0, stream>>>(Qb, Kb, Vt, rzb, OP);
        oproj_kernel<1><<<pg, 256, 0, stream>>>(OP, OP + M, Wo, bo, out);
    } else {
        attn2<1><<<dim3(16, NB * NH, 1), 256, 0, stream>>>(Qb, Kb, Vt, rzb, OP);
        oproj_kernel<0><<<pg, 256, 0, stream>>>(OP, OP, Wo, bo, out);
    }
}

// Round 4
// 476.830 us; speedup vs baseline: 2.1173x; 1.1129x over previous
//
#include <hip/hip_runtime.h>

// MultiHeadattention: B=2, S=2048, D=1024, H=16, Dk=64.
// QUIRK: softmax over the HEAD axis (dim=1): attn[b,h,q,k] = exp(s)/sum_h' exp(s').
// Pipeline:
//   cvt_x: x fp32 -> xb bf16 (once)
//   3x gemm (A=bf16 via global_load_lds, B=W fp32 converted in staging; 128x64 tile)
//   zker:  rz[b][q][k] = 1/sum_h exp(S_h[q,k]*scale)   (register-only head reduction)
//   attn2<KS>: recompute S^T per head, p = exp(s)*rz, full-K PV; KS=4 for occupancy
//   psum:  fold KS bf16 partials -> OPs
//   gemm<2>: out-projection, fp32 out.
// ws aliasing: rz overlaps xb (xb dead after projs); OPs overlaps Qb (dead after attn2).

#define D_MODEL 1024
#define NH 16
#define DKH 64
#define SEQ 2048
#define NB 2
#define NTOK (NB * SEQ)
#define SCALE 0.125f

typedef float f32x4 __attribute__((ext_vector_type(4)));
typedef short bf16x8 __attribute__((ext_vector_type(8)));

static __device__ __forceinline__ float bf2f(unsigned short h) {
    union { unsigned int u; float f; } c; c.u = ((unsigned int)h) << 16; return c.f;
}
static __device__ __forceinline__ unsigned short f2bf(float x) {
    union { float f; unsigned int u; } c; c.f = x;
    unsigned int r = (c.u + 0x7FFFu + ((c.u >> 16) & 1u)) >> 16;
    return (unsigned short)r;
}
static __device__ __forceinline__ unsigned int pack2(float a, float b) {
    return (unsigned int)f2bf(a) | ((unsigned int)f2bf(b) << 16);
}
// one v_perm_b32: result = [hi16(b+rnd) : hi16(a+rnd)]
static __device__ __forceinline__ unsigned int pack2rn(float a, float b) {
    union { float f; unsigned int u; } ca, cb; ca.f = a; cb.f = b;
    return __builtin_amdgcn_perm(cb.u + 0x8000u, ca.u + 0x8000u, 0x07060302u);
}
static __device__ __forceinline__ float bflo(unsigned int u) {
    union { unsigned int x; float f; } c; c.x = u << 16; return c.f;
}
static __device__ __forceinline__ float bfhi(unsigned int u) {
    union { unsigned int x; float f; } c; c.x = u & 0xFFFF0000u; return c.f;
}
static __device__ __forceinline__ f32x4 mfma16(uint4 a, uint4 b, f32x4 c) {
    return __builtin_amdgcn_mfma_f32_16x16x32_bf16(
        __builtin_bit_cast(bf16x8, a), __builtin_bit_cast(bf16x8, b), c, 0, 0, 0);
}
// async global->LDS, 16B per lane; LDS dest = base + lane*16 (wave-uniform base)
static __device__ __forceinline__ void gl_lds16(const unsigned short* g, unsigned short* l) {
    __builtin_amdgcn_global_load_lds(
        (const __attribute__((address_space(1))) unsigned int*)g,
        (__attribute__((address_space(3))) unsigned int*)l, 16, 0, 0);
}

// ---------------- x fp32 -> bf16 ----------------
__global__ __launch_bounds__(256) void cvt_x(const float* __restrict__ x,
                                             unsigned short* __restrict__ xb)
{
    size_t i = ((size_t)blockIdx.x * 256 + threadIdx.x) * 8;
    float4 a = *(const float4*)(x + i);
    float4 b = *(const float4*)(x + i + 4);
    uint4 p = { pack2(a.x, a.y), pack2(a.z, a.w), pack2(b.x, b.y), pack2(b.z, b.w) };
    *(uint4*)(xb + i) = p;
}

// ---------------- GEMM: out[m,n] = sum_k A[m,k]*W[n,k] + bias[n] ----------------
// A bf16 [M][1024] staged via global_load_lds (XOR swizzle folded into global chunk idx).
// W fp32 [1024][1024] converted during staging. BM=128 BN=64 BK=64, 4 waves.
// MODE 0: bf16 [m][n]; MODE 1: bf16 Vt[(b*1024+n)*2048+s]; MODE 2: fp32 [m][n].
template <int MODE>
__global__ __launch_bounds__(256) void gemm_kernel(
    const unsigned short* __restrict__ A, const float* __restrict__ W,
    const float* __restrict__ bias, void* __restrict__ outv)
{
    __shared__ unsigned short lA[128 * 64];  // 16 KB, row-major, swizzled 16B chunks
    __shared__ unsigned short lB[64 * 64];   // 8 KB
    const int tid = threadIdx.x;
    const int wv = tid >> 6, lane = tid & 63, quad = lane >> 4, lm = lane & 15;
    const int m0 = blockIdx.y * 128, n0 = blockIdx.x * 64;

    const int sub = lane >> 3;               // 0..7 (row within 8-row group)
    const int chl = (lane & 7) ^ sub;        // global chunk so LDS[row][lane&7]=G[row][(lane&7)^(row&7)]
    const int brow = tid >> 2, bpart = tid & 3;  // B staging: row 0..63, 16 floats each

    f32x4 acc[2][4] = {};

    for (int k0 = 0; k0 < D_MODEL; k0 += 64) {
        __syncthreads();
        // A: 4 async 8-row loads per wave
#pragma unroll
        for (int j = 0; j < 4; ++j) {
            int rbase = wv * 32 + j * 8;
            const unsigned short* gp = A + (size_t)(m0 + rbase + sub) * D_MODEL + k0 + chl * 8;
            gl_lds16(gp, &lA[rbase * 64]);
        }
        // B: fp32 -> bf16, 16 floats per thread
        {
            const float* gb = W + (size_t)(n0 + brow) * D_MODEL + k0 + bpart * 16;
            float4 f0 = *(const float4*)gb;
            float4 f1 = *(const float4*)(gb + 4);
            float4 f2 = *(const float4*)(gb + 8);
            float4 f3 = *(const float4*)(gb + 12);
            uint4 p0 = { pack2(f0.x, f0.y), pack2(f0.z, f0.w), pack2(f1.x, f1.y), pack2(f1.z, f1.w) };
            uint4 p1 = { pack2(f2.x, f2.y), pack2(f2.z, f2.w), pack2(f3.x, f3.y), pack2(f3.z, f3.w) };
            int c0 = (bpart * 2) ^ (brow & 7), c1 = (bpart * 2 + 1) ^ (brow & 7);
            *(uint4*)&lB[brow * 64 + c0 * 8] = p0;
            *(uint4*)&lB[brow * 64 + c1 * 8] = p1;
        }
        __syncthreads();
#pragma unroll
        for (int ks = 0; ks < 2; ++ks) {
            uint4 af[2];
#pragma unroll
            for (int mt = 0; mt < 2; ++mt)
                af[mt] = *(const uint4*)&lA[(wv * 32 + mt * 16 + lm) * 64 +
                                            ((ks * 4 + quad) ^ (lm & 7)) * 8];
#pragma unroll
            for (int nt = 0; nt < 4; ++nt) {
                uint4 bf = *(const uint4*)&lB[(nt * 16 + lm) * 64 +
                                              ((ks * 4 + quad) ^ (lm & 7)) * 8];
                acc[0][nt] = mfma16(af[0], bf, acc[0][nt]);
                acc[1][nt] = mfma16(af[1], bf, acc[1][nt]);
            }
        }
    }
#pragma unroll
    for (int nt = 0; nt < 4; ++nt) {
        int n = n0 + nt * 16 + lm;
        float bv = bias[n];
#pragma unroll
        for (int mt = 0; mt < 2; ++mt)
#pragma unroll
            for (int r = 0; r < 4; ++r) {
                int m = m0 + wv * 32 + mt * 16 + quad * 4 + r;
                float v = acc[mt][nt][r] + bv;
                if (MODE == 0) {
                    ((unsigned short*)outv)[(size_t)m * D_MODEL + n] = f2bf(v);
                } else if (MODE == 1) {
                    int bi = m >> 11, s = m & 2047;
                    ((unsigned short*)outv)[((size_t)(bi * D_MODEL + n)) * SEQ + s] = f2bf(v);
                } else {
                    ((float*)outv)[(size_t)m * D_MODEL + n] = v;
                }
            }
    }
}

// ---------------- rz[b][q][k] = 1/sum_h exp(S_h[q,k]*scale) ----------------
__global__ __launch_bounds__(256, 4) void zker(
    const unsigned short* __restrict__ Qb, const unsigned short* __restrict__ Kb,
    unsigned short* __restrict__ rz)
{
    const int tid = threadIdx.x;
    const int wv = tid >> 6, lane = tid & 63, quad = lane >> 4, lm = lane & 15;
    const int kb = blockIdx.x, qb = blockIdx.y, b = blockIdx.z;
    const int q0w = qb * 64 + wv * 16;
    const int k0 = kb * 64;

    const unsigned short* qrow = Qb + (size_t)(b * SEQ + q0w + lm) * D_MODEL + quad * 8;
    const unsigned short* krow = Kb + (size_t)(b * SEQ + k0 + lm) * D_MODEL + quad * 8;

    f32x4 z[4] = {};

#pragma unroll
    for (int h = 0; h < NH; ++h) {
        uint4 af0 = *(const uint4*)(qrow + h * DKH);
        uint4 af1 = *(const uint4*)(qrow + h * DKH + 32);
#pragma unroll
        for (int ksub = 0; ksub < 4; ++ksub) {
            const unsigned short* kr = krow + (size_t)ksub * 16 * D_MODEL + h * DKH;
            uint4 bf0 = *(const uint4*)kr;
            uint4 bf1 = *(const uint4*)(kr + 32);
            f32x4 sf = {0.f, 0.f, 0.f, 0.f};
            sf = mfma16(af0, bf0, sf);
            sf = mfma16(af1, bf1, sf);
#pragma unroll
            for (int r = 0; r < 4; ++r)
                z[ksub][r] += __expf(sf[r] * SCALE);
        }
    }
#pragma unroll
    for (int ksub = 0; ksub < 4; ++ksub)
#pragma unroll
        for (int r = 0; r < 4; ++r)
            rz[(size_t)(b * SEQ + q0w + quad * 4 + r) * SEQ + k0 + ksub * 16 + lm] =
                f2bf(1.0f / z[ksub][r]);
}

// ---------------- per-head attention with precomputed rz ----------------
template <int KS>
__global__ __launch_bounds__(256, 2) void attn2(
    const unsigned short* __restrict__ Qb, const unsigned short* __restrict__ Kb,
    const unsigned short* __restrict__ Vt, const unsigned short* __restrict__ rz,
    unsigned short* __restrict__ OP)
{
    const int tid = threadIdx.x;
    const int wv = tid >> 6, lane = tid & 63, quad = lane >> 4, lm = lane & 15;
    const int qb = blockIdx.x;
    const int bh = blockIdx.y, b = bh >> 4, h = bh & 15;
    const int ksl = blockIdx.z;
    const int nk = SEQ / KS;
    const int kbeg = ksl * nk;
    const int q0w = qb * 128 + wv * 32;

    uint4 qf[2][2];
#pragma unroll
    for (int qs = 0; qs < 2; ++qs)
#pragma unroll
        for (int ks = 0; ks < 2; ++ks)
            qf[qs][ks] = *(const uint4*)(Qb +
                (size_t)(b * SEQ + q0w + qs * 16 + lm) * D_MODEL +
                h * DKH + ks * 32 + quad * 8);

    const int perm = ((lm >> 2) * 8) + (lm & 3);
    const unsigned short* kp = Kb + (size_t)(b * SEQ + kbeg + perm) * D_MODEL + h * DKH + quad * 8;
    const unsigned short* vp = Vt + (size_t)(b * D_MODEL + h * DKH + lm) * SEQ + kbeg + quad * 8;
    const unsigned short* rp = rz + (size_t)(b * SEQ + q0w + lm) * SEQ + kbeg + quad * 8;

    f32x4 oa[4][2] = {};

    for (int kt = 0; kt < nk / 32; ++kt) {
        uint4 kf[2][2];
#pragma unroll
        for (int sel = 0; sel < 2; ++sel)
#pragma unroll
            for (int ks = 0; ks < 2; ++ks)
                kf[sel][ks] = *(const uint4*)(kp + (size_t)sel * 4 * D_MODEL + ks * 32);

        f32x4 sf[2][2] = {};
#pragma unroll
        for (int sel = 0; sel < 2; ++sel)
#pragma unroll
            for (int qs = 0; qs < 2; ++qs)
#pragma unroll
                for (int ks = 0; ks < 2; ++ks)
                    sf[sel][qs] = mfma16(kf[sel][ks], qf[qs][ks], sf[sel][qs]);

        uint2 rv[2][2];
#pragma unroll
        for (int qs = 0; qs < 2; ++qs)
#pragma unroll
            for (int sel = 0; sel < 2; ++sel)
                rv[qs][sel] = *(const uint2*)(rp + (size_t)qs * 16 * SEQ + sel * 4);

        uint4 pk[2];
#pragma unroll
        for (int qs = 0; qs < 2; ++qs) {
            float p[2][4];
#pragma unroll
            for (int sel = 0; sel < 2; ++sel) {
                unsigned int rx = rv[qs][sel].x, ry = rv[qs][sel].y;
                p[sel][0] = __expf(sf[sel][qs][0] * SCALE) * bflo(rx);
                p[sel][1] = __expf(sf[sel][qs][1] * SCALE) * bfhi(rx);
                p[sel][2] = __expf(sf[sel][qs][2] * SCALE) * bflo(ry);
                p[sel][3] = __expf(sf[sel][qs][3] * SCALE) * bfhi(ry);
            }
            pk[qs].x = pack2rn(p[0][0], p[0][1]);
            pk[qs].y = pack2rn(p[0][2], p[0][3]);
            pk[qs].z = pack2rn(p[1][0], p[1][1]);
            pk[qs].w = pack2rn(p[1][2], p[1][3]);
        }

#pragma unroll
        for (int ct = 0; ct < 4; ++ct) {
            uint4 vf = *(const uint4*)(vp + (size_t)ct * 16 * SEQ);
            oa[ct][0] = mfma16(vf, pk[0], oa[ct][0]);
            oa[ct][1] = mfma16(vf, pk[1], oa[ct][1]);
        }
        kp += 32 * (size_t)D_MODEL;   // key-row stride
        vp += 32; rp += 32;
    }

    unsigned short* op = OP + (size_t)ksl * NTOK * D_MODEL;
#pragma unroll
    for (int ct = 0; ct < 4; ++ct)
#pragma unroll
        for (int qs = 0; qs < 2; ++qs) {
            uint2 st = { pack2rn(oa[ct][qs][0], oa[ct][qs][1]),
                         pack2rn(oa[ct][qs][2], oa[ct][qs][3]) };
            *(uint2*)(op + (size_t)(b * SEQ + q0w + qs * 16 + lm) * D_MODEL +
                      h * DKH + ct * 16 + quad * 4) = st;
        }
}

// ---------------- fold KS bf16 partials ----------------
template <int KS>
__global__ __launch_bounds__(256) void psum(const unsigned short* __restrict__ OP,
                                            unsigned short* __restrict__ OPs)
{
    const size_t M = (size_t)NTOK * D_MODEL;
    size_t i = ((size_t)blockIdx.x * 256 + threadIdx.x) * 8;
    uint4 a = *(const uint4*)(OP + i);
    float lo0 = bflo(a.x), hi0 = bfhi(a.x), lo1 = bflo(a.y), hi1 = bfhi(a.y);
    float lo2 = bflo(a.z), hi2 = bfhi(a.z), lo3 = bflo(a.w), hi3 = bfhi(a.w);
#pragma unroll
    for (int p = 1; p < KS; ++p) {
        uint4 u = *(const uint4*)(OP + p * M + i);
        lo0 += bflo(u.x); hi0 += bfhi(u.x); lo1 += bflo(u.y); hi1 += bfhi(u.y);
        lo2 += bflo(u.z); hi2 += bfhi(u.z); lo3 += bflo(u.w); hi3 += bfhi(u.w);
    }
    uint4 o = { pack2(lo0, hi0), pack2(lo1, hi1), pack2(lo2, hi2), pack2(lo3, hi3) };
    *(uint4*)(OPs + i) = o;
}

extern "C" void kernel_launch(void* const* d_in, const int* in_sizes, int n_in,
                              void* d_out, int out_size, void* d_ws, size_t ws_size,
                              hipStream_t stream)
{
    const float* x  = (const float*)d_in[0];
    const float* Wq = (const float*)d_in[1];
    const float* bq = (const float*)d_in[2];
    const float* Wk = (const float*)d_in[3];
    const float* bk = (const float*)d_in[4];
    const float* Wv = (const float*)d_in[5];
    const float* bv = (const float*)d_in[6];
    const float* Wo = (const float*)d_in[7];
    const float* bo = (const float*)d_in[8];
    float* out = (float*)d_out;

    const size_t M = (size_t)NTOK * D_MODEL;       // 4,194,304 elems
    const size_t RZ = (size_t)NB * SEQ * SEQ;      // 8,388,608 elems
    unsigned short* ws = (unsigned short*)d_ws;
    unsigned short* xb  = ws;            // bf16 [4096][1024]; rz overlaps (xb dead after projs)
    unsigned short* rzb = ws;            // bf16 [2][2048][2048]
    unsigned short* Qb  = ws + RZ;       // bf16 [4096][1024]
    unsigned short* Kb  = Qb + M;
    unsigned short* Vt  = Kb + M;        // bf16 [2][1024][2048] transposed
    unsigned short* OP  = Vt + M;        // KS partials
    unsigned short* OPs = Qb;            // alias: Qb dead after attn2

    const size_t need4 = (RZ + 3 * M + 4 * M) * sizeof(unsigned short);  // 75.5 MB
    const size_t need2 = (RZ + 3 * M + 2 * M) * sizeof(unsigned short);  // 58.7 MB (proven)
    const int KS = (ws_size >= need4) ? 4 : (ws_size >= need2) ? 2 : 1;

    cvt_x<<<2048, 256, 0, stream>>>(x, xb);
    dim3 gg(16, 32);
    gemm_kernel<0><<<gg, 256, 0, stream>>>(xb, Wq, bq, Qb);
    gemm_kernel<0><<<gg, 256, 0, stream>>>(xb, Wk, bk, Kb);
    gemm_kernel<1><<<gg, 256, 0, stream>>>(xb, Wv, bv, Vt);
    zker<<<dim3(32, 32, NB), 256, 0, stream>>>(Qb, Kb, rzb);
    if (KS == 4) {
        attn2<4><<<dim3(16, NB * NH, 4), 256, 0, stream>>>(Qb, Kb, Vt, rzb, OP);
        psum<4><<<2048, 256, 0, stream>>>(OP, OPs);
    } else if (KS == 2) {
        attn2<2><<<dim3(16, NB * NH, 2), 256, 0, stream>>>(Qb, Kb, Vt, rzb, OP);
        psum<2><<<2048, 256, 0, stream>>>(OP, OPs);
    } else {
        attn2<1><<<dim3(16, NB * NH, 1), 256, 0, stream>>>(Qb, Kb, Vt, rzb, OP);
        OPs = OP;
    }
    gemm_kernel<2><<<gg, 256, 0, stream>>>(OPs, Wo, bo, out);
}